// Round 1
// 2709.695 us; speedup vs baseline: 1.5337x; 1.5337x over previous
//
#include <hip/hip_runtime.h>

// LSTM scan, fused x@W_ih.T + h@W_hh.T, bf16 MFMA 16x16x32.
// 256 WGs = 8 batch-groups(32 batches) x 32 members(16 hidden units / 64 gate rows).
// W B-fragments REGISTER-RESIDENT per wave (step-invariant, 256 VGPR).
// Cross-WG h exchange through LLC via RELAXED agent-scope atomics only.
// R2 changes vs 4.15ms baseline:
//  (1) x(t+1) prefetched via global_load_lds into a 2x64KB LDS ring
//      (reuses the dead W-staging LDS region) -> x HBM-miss latency off the
//      per-step chain; per-WG global x traffic halved (one shared copy).
//  (2) flag load issued BEFORE the DMA and before the x-MFMA phase -> its
//      LLC round-trip hides under compute; poll loop rarely entered.
//  (3) only the h-exchange store is drained before the flag post; out/hidb
//      HBM stores moved after the flag (drain in next step's slack).
//  (4) dones preloaded once into LDS (u8 keeps) -> no per-step global load
//      in the pre-barrier drain.

#define T_STEPS 256
#define BATCH   256
#define INP     512
#define HID     512
#define GROUPS  8
#define MEMB    32
#define BT      32          // batches per group
#define NWG     (GROUPS*MEMB)
#define NTHR    256
#define XBUF    65536       // one x step-slice: 32 rows x 512 f32
#define K8OFF   (2*XBUF)
#define LDS_BYTES (2*XBUF + T_STEPS*BT)   // 139264

typedef float  f32x4  __attribute__((ext_vector_type(4)));
typedef short  bf16x8 __attribute__((ext_vector_type(8)));

typedef const __attribute__((address_space(1))) void gas_v;
typedef __attribute__((address_space(3))) void las_v;
__device__ __forceinline__ void gld_lds16(const void* g, void* l) {
  __builtin_amdgcn_global_load_lds((gas_v*)g, (las_v*)l, 16, 0, 0);
}

__device__ __forceinline__ unsigned short f2bf(float f) {
  unsigned u = __builtin_bit_cast(unsigned, f);
  return (unsigned short)((u + 0x8000u) >> 16);
}
__device__ __forceinline__ bf16x8 cvt8(float4 a, float4 b) {
  bf16x8 v;
  v[0]=(short)f2bf(a.x); v[1]=(short)f2bf(a.y); v[2]=(short)f2bf(a.z); v[3]=(short)f2bf(a.w);
  v[4]=(short)f2bf(b.x); v[5]=(short)f2bf(b.y); v[6]=(short)f2bf(b.z); v[7]=(short)f2bf(b.w);
  return v;
}
__device__ __forceinline__ float sigf(float x) {
  return __fdividef(1.0f, 1.0f + __expf(-x));
}
__device__ __forceinline__ float tanh_(float x) {
  float e = __expf(-2.0f * fabsf(x));
  float t = __fdividef(1.0f - e, 1.0f + e);
  return copysignf(t, x);
}
__device__ __forceinline__ f32x4 shflx4(f32x4 v, int m) {
  f32x4 r;
  r[0]=__shfl_xor(v[0],m,64); r[1]=__shfl_xor(v[1],m,64);
  r[2]=__shfl_xor(v[2],m,64); r[3]=__shfl_xor(v[3],m,64);
  return r;
}

__global__ void __launch_bounds__(NTHR, 1)
lstm_fused(const float* __restrict__ x, const int* __restrict__ dones,
           const float* __restrict__ Wih, const float* __restrict__ Whh,
           const float* __restrict__ bih, const float* __restrict__ bhh,
           float* __restrict__ out, unsigned* __restrict__ hb32,
           unsigned long long* __restrict__ hb64, int* __restrict__ flags)
{
  extern __shared__ char smem_raw[];
  unsigned short* wst  = (unsigned short*)smem_raw;        // init only, [0,128K)
  char*           xring = smem_raw;                        // loop: 2 x 64KB
  unsigned char*  k8   = (unsigned char*)smem_raw + K8OFF; // keeps[T][BT]

  const int tid  = threadIdx.x;
  const int lane = tid & 63;
  const int wv   = tid >> 6;
  const int grp  = blockIdx.x >> 5;
  const int memb = blockIdx.x & 31;
  const int b0   = grp * BT;
  const int j0   = memb * 16;
  const int mtile = wv & 1;        // which 16-batch M tile
  const int hh    = wv >> 1;       // which hidden octet of the member's 16
  const int q    = lane >> 4;
  const int n    = lane & 15;
  const int r    = n & 7;

  // ---- one-time: W slice (64 gate rows x concat-K 1024) -> LDS, B-frag order
  for (int e = tid; e < 64*1024; e += NTHR) {
    int s = e >> 10, k = e & 1023;
    int nf = s >> 4, nn = s & 15;
    int gp = nf & 1;
    int hloc = (nf >> 1)*8 + (nn & 7);
    int gate = (nn < 8) ? (gp ? 2 : 0) : (gp ? 3 : 1);
    int grow = gate*HID + j0 + hloc;
    float v = (k < INP) ? Wih[grow*INP + k] : Whh[grow*HID + (k - INP)];
    int kk = k >> 5, qq = (k >> 3) & 3, j = k & 7;
    wst[((kk*4 + nf)*64 + qq*16 + nn)*8 + j] = f2bf(v);
  }
  // ---- one-time: all keeps -> LDS (u8), removes per-step dones load
  for (int idx = tid; idx < T_STEPS*BT; idx += NTHR) {
    int tt = idx >> 5, bb = idx & 31;
    k8[idx] = (unsigned char)(1 - dones[tt*BATCH + b0 + bb]);
  }
  __syncthreads();

  // ---- B fragments into registers (step-invariant). 64 x bf16x8 = 256 VGPR.
  const int nf0 = 2*hh;
  bf16x8 B0[32], B1[32];
  #pragma unroll
  for (int kk = 0; kk < 32; ++kk) {
    B0[kk] = *(const bf16x8*)(wst + ((kk*4 + nf0    )*64 + lane)*8);
    B1[kk] = *(const bf16x8*)(wst + ((kk*4 + nf0 + 1)*64 + lane)*8);
  }
  __syncthreads();   // W-staging LDS now dead; xring may overwrite it

  const int jmy = j0 + hh*8 + r;   // this lane's hidden unit
  const float bi  = bih[0*HID + jmy] + bhh[0*HID + jmy];
  const float bf_ = bih[1*HID + jmy] + bhh[1*HID + jmy];
  const float bg  = bih[2*HID + jmy] + bhh[2*HID + jmy];
  const float bo  = bih[3*HID + jmy] + bhh[3*HID + jmy];

  float h_s[2] = {0.f, 0.f}, c_s[2] = {0.f, 0.f};
  const bool lo  = (n < 8);
  const int  rgb = lo ? 0 : 2;
  float* hidb = out + (size_t)T_STEPS*BATCH*HID;
  const int bbA = b0 + mtile*16 + n;        // A-row batch for MFMA loads
  const bf16x8 zf = {0,0,0,0,0,0,0,0};

  // DMA of one x step-slice into the LDS ring, fragment-ordered so the
  // per-lane GLOBAL address does the swizzle (LDS dest is linear per wave).
  // slot byte B = e*4096 | tid*16 decodes to (mt,kk,qq,nn,j):
  //   mt=e>>3  kk=(e&7)*2|(tid>>7)  qq=(tid>>5)&3  nn=(tid>>1)&15  j=tid&1
  auto stage_x = [&](int ts) {
    char* wbase = xring + (ts & 1)*XBUF + (tid & 192)*16;  // + wv*1024
    const int nn   = (tid >> 1) & 15;
    const int col0 = ((tid >> 7) << 5) + ((tid >> 5) & 3)*8 + (tid & 1)*4;
    const float* rowb = x + (size_t)(ts*BATCH + b0)*INP;
    #pragma unroll
    for (int e = 0; e < 16; ++e) {
      int row = (e >> 3)*16 + nn;
      int col = col0 + (e & 7)*64;
      gld_lds16(rowb + (size_t)row*INP + col, wbase + e*4096);
    }
  };

  // ---- prologue: x(0) into buf 0
  stage_x(0);
  asm volatile("s_waitcnt vmcnt(0)" ::: "memory");
  __syncthreads();

  for (int t = 0; t < T_STEPS; ++t) {
    // ---- early flag load (BEFORE the DMA so its waitcnt doesn't fence it);
    //      its LLC round-trip hides under the x-MFMA phase below.
    const int* fp = flags + grp*MEMB + lane;
    int fv = t;
    if (t > 0 && lane < MEMB)
      fv = __hip_atomic_load(fp, __ATOMIC_RELAXED, __HIP_MEMORY_SCOPE_AGENT);

    // ---- issue DMA of x(t+1); drains during this whole step
    if (t + 1 < T_STEPS) stage_x(t + 1);

    // ---- x part from LDS: no peer dependence, no global-miss latency
    f32x4 acc0 = {0.f,0.f,0.f,0.f}, acc1 = {0.f,0.f,0.f,0.f};
    const char* xb = xring + (t & 1)*XBUF + mtile*32768 + lane*32;
    #pragma unroll
    for (int kk = 0; kk < 16; ++kk) {
      float4 xa = *(const float4*)(xb + kk*2048);
      float4 xc = *(const float4*)(xb + kk*2048 + 16);
      bf16x8 a = cvt8(xa, xc);
      acc0 = __builtin_amdgcn_mfma_f32_16x16x32_bf16(a, B0[kk], acc0, 0, 0, 0);
      acc1 = __builtin_amdgcn_mfma_f32_16x16x32_bf16(a, B1[kk], acc1, 0, 0, 0);
    }

    // ---- wait for peers' h(t-1): in steady state fv is already >= t
    if (t > 0) {
      while (!__all(fv >= t)) {
        __builtin_amdgcn_s_sleep(1);
        fv = (lane < MEMB)
           ? __hip_atomic_load(fp, __ATOMIC_RELAXED, __HIP_MEMORY_SCOPE_AGENT)
           : t;
      }
      asm volatile("" ::: "memory");
    }

    // ---- h part: A rows from LLC (relaxed agent 8B atomics), keep-masked
    const unsigned char kA = k8[t*BT + mtile*16 + n];
    unsigned long long* hb =
        hb64 + ((t+1)&1)*(BATCH*HID/4) + (size_t)bbA*(HID/4);
    #pragma unroll
    for (int kk = 0; kk < 16; ++kk) {
      union { unsigned long long u[2]; bf16x8 v; } au;
      au.u[0] = __hip_atomic_load(hb + kk*8 + 2*q,     __ATOMIC_RELAXED, __HIP_MEMORY_SCOPE_AGENT);
      au.u[1] = __hip_atomic_load(hb + kk*8 + 2*q + 1, __ATOMIC_RELAXED, __HIP_MEMORY_SCOPE_AGENT);
      bf16x8 a = au.v;
      if (!kA) a = zf;
      acc0 = __builtin_amdgcn_mfma_f32_16x16x32_bf16(a, B0[16+kk], acc0, 0, 0, 0);
      acc1 = __builtin_amdgcn_mfma_f32_16x16x32_bf16(a, B1[16+kk], acc1, 0, 0, 0);
    }

    // ---- gates: lanes n and n^8 swap halves (i,f in acc0; g,o in acc1) ----
    f32x4 oa = shflx4(acc0, 8), ob = shflx4(acc1, 8);
    f32x4 I = lo ? acc0 : oa;
    f32x4 F = lo ? oa : acc0;
    f32x4 G = lo ? acc1 : ob;
    f32x4 O = lo ? ob : acc1;

    float hnv[2], hrv[2], crv[2];
    #pragma unroll
    for (int u = 0; u < 2; ++u) {
      int rg = rgb + u;
      int lb = mtile*16 + q*4 + rg;
      float kp = (float)k8[t*BT + lb];
      float hr = h_s[u]*kp, cr = c_s[u]*kp;
      float iv = sigf (I[rg] + bi);
      float fv_ = sigf (F[rg] + bf_);
      float gv = tanh_(G[rg] + bg);
      float ov = sigf (O[rg] + bo);
      float cn = fv_*cr + iv*gv;
      float hn = ov*tanh_(cn);
      h_s[u] = hn; c_s[u] = cn;
      hnv[u] = hn; hrv[u] = hr; crv[u] = cr;
    }

    // ---- h(t) -> LLC: pair adjacent hids via shfl_xor(1), one dword/lane
    {
      float send  = (n & 1) ? hnv[0] : hnv[1];
      float other = __shfl_xor(send, 1, 64);
      int lb0 = mtile*16 + q*4 + rgb;
      int lbm = (n & 1) ? lb0 + 1 : lb0;
      unsigned lo16 = (n & 1) ? (unsigned)f2bf(other)  : (unsigned)f2bf(hnv[0]);
      unsigned hi16 = (n & 1) ? (unsigned)f2bf(hnv[1]) : (unsigned)f2bf(other);
      unsigned dw = lo16 | (hi16 << 16);
      unsigned* dst = hb32 + (t&1)*(BATCH*HID/2)
                    + (size_t)(b0 + lbm)*(HID/2) + (jmy >> 1);
      __hip_atomic_store(dst, dw, __ATOMIC_RELAXED, __HIP_MEMORY_SCOPE_AGENT);
    }

    // ---- drain (h-exchange + long-since-issued DMA only), barrier, flag
    asm volatile("s_waitcnt vmcnt(0)" ::: "memory");
    __syncthreads();
    if (tid == 0)
      __hip_atomic_store(flags + grp*MEMB + memb, t + 1,
                         __ATOMIC_RELAXED, __HIP_MEMORY_SCOPE_AGENT);

    // ---- out/hidb HBM stores AFTER the flag post: off the critical path,
    //      drained by next step's pre-flag vmcnt(0) a full step later.
    #pragma unroll
    for (int u = 0; u < 2; ++u) {
      int lb = mtile*16 + q*4 + rgb + u;
      int bb = b0 + lb;
      out [(size_t)(t*BATCH + bb)*HID + jmy]       = hnv[u];
      hidb[((size_t)(t*2+0)*BATCH + bb)*HID + jmy] = hrv[u];
      hidb[((size_t)(t*2+1)*BATCH + bb)*HID + jmy] = crv[u];
    }
  }
}

extern "C" void kernel_launch(void* const* d_in, const int* in_sizes, int n_in,
                              void* d_out, int out_size, void* d_ws, size_t ws_size,
                              hipStream_t stream) {
  (void)in_sizes; (void)n_in; (void)out_size; (void)ws_size;
  const float* x   = (const float*)d_in[0];
  const int*   dn  = (const int*)  d_in[1];
  const float* Wih = (const float*)d_in[2];
  const float* Whh = (const float*)d_in[3];
  const float* bih = (const float*)d_in[4];
  const float* bhh = (const float*)d_in[5];
  float* out = (float*)d_out;

  unsigned*           hb32 = (unsigned*)d_ws;
  unsigned long long* hb64 = (unsigned long long*)d_ws;
  size_t hbuf_bytes = (size_t)2*BATCH*HID*sizeof(unsigned short);   // 512 KB
  int* flags = (int*)((char*)d_ws + hbuf_bytes);
  size_t clear_bytes = hbuf_bytes + NWG*sizeof(int);

  hipMemsetAsync(d_ws, 0, clear_bytes, stream);   // zero h(-1) + flags
  hipFuncSetAttribute((const void*)lstm_fused,
                      hipFuncAttributeMaxDynamicSharedMemorySize, LDS_BYTES);
  lstm_fused<<<dim3(NWG), dim3(NTHR), LDS_BYTES, stream>>>(
      x, dn, Wih, Whh, bih, bhh, out, hb32, hb64, flags);
}

// Round 2
// 2019.716 us; speedup vs baseline: 2.0576x; 1.3416x over previous
//
#include <hip/hip_runtime.h>

// LSTM scan, fused x@W_ih.T + h@W_hh.T, bf16 MFMA 16x16x32.
// 256 WGs = 8 batch-groups(32 batches) x 32 members(16 hidden units / 64 gate rows).
// W B-fragments register/AGPR-resident per wave (step-invariant).
// R3: FLAG-FREE, BARRIER-FREE self-validating h exchange.
//  - |h| < 1 strictly => bit14 of every bf16 is 0. Embed seq bit c=(t>>1)&1
//    in bit14 of stored h; consumers validate freshness per-dword and retry.
//    Distinguishes step t-1 data from stale t-3 data in the same slot.
//  - h loads: plain global_load_dwordx4 sc0 sc1 (LLC-coherent, NON-atomic,
//    line rate, half the op count of the old 2x8B atomics).
//  - No flags, no polls, no s_sleep, no store-ack vmcnt before a flag, no
//    per-step __syncthreads. Ring/slot safety by dataflow: validating peer
//    h(t) proves that peer finished reading slot t-1 (its stores depend on
//    its loads); x-ring fenced because each wave DMAs its OWN half and the
//    h-load asm's vmcnt(0) retires last step's DMA.
//  - x-ring XOR-swizzled (chunk ^= bit3) via pre-swizzled DMA source addrs:
//    kills the ds_read_b128 bank conflicts (was 536 cy/WG/step).
//  - h(-1): memset 0x40 pattern => parity bit 1, masked to ~3e-39 ~= 0.

#define T_STEPS 256
#define BATCH   256
#define INP     512
#define HID     512
#define GROUPS  8
#define MEMB    32
#define BT      32          // batches per group
#define NWG     (GROUPS*MEMB)
#define NTHR    256
#define XBUF    65536       // one x step-slice: 32 rows x 512 f32
#define K8OFF   (2*XBUF)
#define LDS_BYTES (2*XBUF + T_STEPS*BT)   // 139264
#define PARM    0x40004000u               // bf16 bit14 pair mask

typedef float  f32x4  __attribute__((ext_vector_type(4)));
typedef short  bf16x8 __attribute__((ext_vector_type(8)));
typedef unsigned int u32x4 __attribute__((ext_vector_type(4)));

struct HF { u32x4 h[16]; };

typedef const __attribute__((address_space(1))) void gas_v;
typedef __attribute__((address_space(3))) void las_v;
__device__ __forceinline__ void gld_lds16(const void* g, void* l) {
  __builtin_amdgcn_global_load_lds((gas_v*)g, (las_v*)l, 16, 0, 0);
}

__device__ __forceinline__ unsigned short f2bf(float f) {
  unsigned u = __builtin_bit_cast(unsigned, f);
  return (unsigned short)((u + 0x8000u) >> 16);
}
__device__ __forceinline__ bf16x8 cvt8(float4 a, float4 b) {
  bf16x8 v;
  v[0]=(short)f2bf(a.x); v[1]=(short)f2bf(a.y); v[2]=(short)f2bf(a.z); v[3]=(short)f2bf(a.w);
  v[4]=(short)f2bf(b.x); v[5]=(short)f2bf(b.y); v[6]=(short)f2bf(b.z); v[7]=(short)f2bf(b.w);
  return v;
}
__device__ __forceinline__ float sigf(float x) {
  return __fdividef(1.0f, 1.0f + __expf(-x));
}
__device__ __forceinline__ float tanh_(float x) {
  float e = __expf(-2.0f * fabsf(x));
  float t = __fdividef(1.0f - e, 1.0f + e);
  return copysignf(t, x);
}
__device__ __forceinline__ f32x4 shflx4(f32x4 v, int m) {
  f32x4 r;
  r[0]=__shfl_xor(v[0],m,64); r[1]=__shfl_xor(v[1],m,64);
  r[2]=__shfl_xor(v[2],m,64); r[3]=__shfl_xor(v[3],m,64);
  return r;
}

// 16 x 16B LLC-coherent loads (one batch-row fragment set), single drain.
__device__ __forceinline__ void llc_load_h(HF& o, const void* p) {
  unsigned long long a = (unsigned long long)p;
  asm volatile(
    "global_load_dwordx4 %[h0],  %[a], off sc0 sc1\n\t"
    "global_load_dwordx4 %[h1],  %[a], off offset:64 sc0 sc1\n\t"
    "global_load_dwordx4 %[h2],  %[a], off offset:128 sc0 sc1\n\t"
    "global_load_dwordx4 %[h3],  %[a], off offset:192 sc0 sc1\n\t"
    "global_load_dwordx4 %[h4],  %[a], off offset:256 sc0 sc1\n\t"
    "global_load_dwordx4 %[h5],  %[a], off offset:320 sc0 sc1\n\t"
    "global_load_dwordx4 %[h6],  %[a], off offset:384 sc0 sc1\n\t"
    "global_load_dwordx4 %[h7],  %[a], off offset:448 sc0 sc1\n\t"
    "global_load_dwordx4 %[h8],  %[a], off offset:512 sc0 sc1\n\t"
    "global_load_dwordx4 %[h9],  %[a], off offset:576 sc0 sc1\n\t"
    "global_load_dwordx4 %[h10], %[a], off offset:640 sc0 sc1\n\t"
    "global_load_dwordx4 %[h11], %[a], off offset:704 sc0 sc1\n\t"
    "global_load_dwordx4 %[h12], %[a], off offset:768 sc0 sc1\n\t"
    "global_load_dwordx4 %[h13], %[a], off offset:832 sc0 sc1\n\t"
    "global_load_dwordx4 %[h14], %[a], off offset:896 sc0 sc1\n\t"
    "global_load_dwordx4 %[h15], %[a], off offset:960 sc0 sc1\n\t"
    "s_waitcnt vmcnt(0)"
    : [h0]"=v"(o.h[0]),  [h1]"=v"(o.h[1]),  [h2]"=v"(o.h[2]),  [h3]"=v"(o.h[3]),
      [h4]"=v"(o.h[4]),  [h5]"=v"(o.h[5]),  [h6]"=v"(o.h[6]),  [h7]"=v"(o.h[7]),
      [h8]"=v"(o.h[8]),  [h9]"=v"(o.h[9]),  [h10]"=v"(o.h[10]),[h11]"=v"(o.h[11]),
      [h12]"=v"(o.h[12]),[h13]"=v"(o.h[13]),[h14]"=v"(o.h[14]),[h15]"=v"(o.h[15])
    : [a]"v"(a)
    : "memory");
}

__global__ void __launch_bounds__(NTHR, 1)
lstm_fused(const float* __restrict__ x, const int* __restrict__ dones,
           const float* __restrict__ Wih, const float* __restrict__ Whh,
           const float* __restrict__ bih, const float* __restrict__ bhh,
           float* __restrict__ out, unsigned* __restrict__ hb32,
           unsigned long long* __restrict__ hb64, int* __restrict__ flags)
{
  (void)flags;
  extern __shared__ char smem_raw[];
  unsigned short* wst   = (unsigned short*)smem_raw;        // init only
  char*           xring = smem_raw;                         // loop: 2 x 64KB
  unsigned char*  k8    = (unsigned char*)smem_raw + K8OFF; // keeps[T][BT]

  const int tid  = threadIdx.x;
  const int lane = tid & 63;
  const int wv   = tid >> 6;
  const int grp  = blockIdx.x >> 5;
  const int memb = blockIdx.x & 31;
  const int b0   = grp * BT;
  const int j0   = memb * 16;
  const int mtile = wv & 1;        // which 16-batch M tile
  const int hh    = wv >> 1;       // which hidden octet of the member's 16
  const int q    = lane >> 4;
  const int n    = lane & 15;
  const int r    = n & 7;

  // ---- one-time: W slice (64 gate rows x concat-K 1024) -> LDS, B-frag order
  for (int e = tid; e < 64*1024; e += NTHR) {
    int s = e >> 10, k = e & 1023;
    int nf = s >> 4, nn = s & 15;
    int gp = nf & 1;
    int hloc = (nf >> 1)*8 + (nn & 7);
    int gate = (nn < 8) ? (gp ? 2 : 0) : (gp ? 3 : 1);
    int grow = gate*HID + j0 + hloc;
    float v = (k < INP) ? Wih[grow*INP + k] : Whh[grow*HID + (k - INP)];
    int kk = k >> 5, qq = (k >> 3) & 3, j = k & 7;
    wst[((kk*4 + nf)*64 + qq*16 + nn)*8 + j] = f2bf(v);
  }
  // ---- one-time: all keeps -> LDS (u8)
  for (int idx = tid; idx < T_STEPS*BT; idx += NTHR) {
    int tt = idx >> 5, bb = idx & 31;
    k8[idx] = (unsigned char)(1 - dones[tt*BATCH + b0 + bb]);
  }
  __syncthreads();

  // ---- B fragments into registers/AGPRs (step-invariant).
  const int nf0 = 2*hh;
  bf16x8 B0[32], B1[32];
  #pragma unroll
  for (int kk = 0; kk < 32; ++kk) {
    B0[kk] = *(const bf16x8*)(wst + ((kk*4 + nf0    )*64 + lane)*8);
    B1[kk] = *(const bf16x8*)(wst + ((kk*4 + nf0 + 1)*64 + lane)*8);
  }
  __syncthreads();   // W-staging LDS now dead; xring may overwrite it

  const int jmy = j0 + hh*8 + r;   // this lane's hidden unit
  const float bi  = bih[0*HID + jmy] + bhh[0*HID + jmy];
  const float bf_ = bih[1*HID + jmy] + bhh[1*HID + jmy];
  const float bg  = bih[2*HID + jmy] + bhh[2*HID + jmy];
  const float bo  = bih[3*HID + jmy] + bhh[3*HID + jmy];

  float h_s[2] = {0.f, 0.f}, c_s[2] = {0.f, 0.f};
  const bool lo  = (n < 8);
  const int  rgb = lo ? 0 : 2;
  float* hidb = out + (size_t)T_STEPS*BATCH*HID;
  const int bbA = b0 + mtile*16 + n;        // A-row batch for MFMA loads

  // ---- per-wave DMA of the wave's OWN mtile half (32KB) into the LDS ring.
  // Phys chunk p = e*64 + lane stores logical chunk l = p ^ (p>>3 & 1)
  // (XOR-swizzle so the stride-32B ds_read_b128 x-phase is conflict-free).
  // Logical chunk l = kk*128 + lane_r*2 + half holds
  //   x[batch mtile*16 + (lane_r&15)][k = kk*32 + (lane_r>>4)*8 + half*4 ..+3]
  auto stage_x = [&](int ts) {
    char* base = xring + (ts & 1)*XBUF + mtile*32768;
    const int lp   = lane ^ ((lane >> 3) & 1);
    const int row  = mtile*16 + ((lp >> 1) & 15);
    const int coff = ((lp >> 5) << 3) + (lp & 1)*4;
    const float* src0 = x + (size_t)(ts*BATCH + b0 + row)*INP + coff;
    #pragma unroll
    for (int e = 0; e < 32; ++e)
      gld_lds16(src0 + e*16, base + e*1024);
  };

  // ---- prologue: x(0) into buf 0 (own half; own vmcnt guards own reads)
  stage_x(0);
  asm volatile("s_waitcnt vmcnt(0)" ::: "memory");

  const char* xbase = xring + mtile*32768 + lane*32;
  const int   sx    = ((lane >> 2) & 1) << 4;   // read-side swizzle bit

  for (int t = 0; t < T_STEPS; ++t) {
    // ---- x part from swizzled LDS ring (slot t&1)
    f32x4 acc0 = {0.f,0.f,0.f,0.f}, acc1 = {0.f,0.f,0.f,0.f};
    const char* xb = xbase + (t & 1)*XBUF;
    #pragma unroll
    for (int kk = 0; kk < 16; ++kk) {
      float4 xa = *(const float4*)(xb + kk*2048 + sx);
      float4 xc = *(const float4*)(xb + kk*2048 + (16 ^ sx));
      bf16x8 a = cvt8(xa, xc);
      acc0 = __builtin_amdgcn_mfma_f32_16x16x32_bf16(a, B0[kk], acc0, 0, 0, 0);
      acc1 = __builtin_amdgcn_mfma_f32_16x16x32_bf16(a, B1[kk], acc1, 0, 0, 0);
    }

    // ---- h(t-1) rows: self-validating LLC loads (slot (t-1)&1)
    const void* hbp = (const char*)(hb64 + ((t+1)&1)*(BATCH*HID/4)
                                  + (size_t)bbA*(HID/4)) + q*16;
    HF hf;
    llc_load_h(hf, hbp);

    // ---- issue DMA of x(t+1) now (youngest VMEM; drains over the next
    //      full step, retired by next step's llc_load_h vmcnt(0))
    if (t + 1 < T_STEPS) stage_x(t + 1);

    // ---- validate freshness via embedded bit14 parity; retry if stale
    const int ebit = (t == 0) ? 1 : (((t - 1) >> 1) & 1);
    const unsigned want = ebit ? PARM : 0u;
    while (true) {
      unsigned bad = 0;
      #pragma unroll
      for (int kk = 0; kk < 16; ++kk) {
        u32x4 v = hf.h[kk];
        bad |= (v[0] ^ want) | (v[1] ^ want) | (v[2] ^ want) | (v[3] ^ want);
      }
      if (__all((bad & PARM) == 0u)) break;
      llc_load_h(hf, hbp);
    }

    // ---- h MFMAs (strip parity bit; zero rows where done)
    const unsigned char kA = k8[t*BT + mtile*16 + n];
    const unsigned msk = kA ? (ebit ? ~PARM : 0xFFFFFFFFu) : 0u;
    #pragma unroll
    for (int kk = 0; kk < 16; ++kk) {
      u32x4 v = hf.h[kk];
      v[0] &= msk; v[1] &= msk; v[2] &= msk; v[3] &= msk;
      bf16x8 a = __builtin_bit_cast(bf16x8, v);
      acc0 = __builtin_amdgcn_mfma_f32_16x16x32_bf16(a, B0[16+kk], acc0, 0, 0, 0);
      acc1 = __builtin_amdgcn_mfma_f32_16x16x32_bf16(a, B1[16+kk], acc1, 0, 0, 0);
    }

    // ---- gates: lanes n and n^8 swap halves (i,f in acc0; g,o in acc1) ----
    f32x4 oa = shflx4(acc0, 8), ob = shflx4(acc1, 8);
    f32x4 I = lo ? acc0 : oa;
    f32x4 F = lo ? oa : acc0;
    f32x4 G = lo ? acc1 : ob;
    f32x4 O = lo ? ob : acc1;

    float hnv[2], hrv[2], crv[2];
    #pragma unroll
    for (int u = 0; u < 2; ++u) {
      int rg = rgb + u;
      int lb = mtile*16 + q*4 + rg;
      float kp = (float)k8[t*BT + lb];
      float hr = h_s[u]*kp, cr = c_s[u]*kp;
      float iv  = sigf (I[rg] + bi);
      float fv_ = sigf (F[rg] + bf_);
      float gv  = tanh_(G[rg] + bg);
      float ov  = sigf (O[rg] + bo);
      float cn = fv_*cr + iv*gv;
      float hn = ov*tanh_(cn);
      h_s[u] = hn; c_s[u] = cn;
      hnv[u] = hn; hrv[u] = hr; crv[u] = cr;
    }

    // ---- h(t) -> LLC first (peer-visible ASAP), parity bit embedded
    {
      float send  = (n & 1) ? hnv[0] : hnv[1];
      float other = __shfl_xor(send, 1, 64);
      int lb0 = mtile*16 + q*4 + rgb;
      int lbm = (n & 1) ? lb0 + 1 : lb0;
      unsigned lo16 = (n & 1) ? (unsigned)f2bf(other)  : (unsigned)f2bf(hnv[0]);
      unsigned hi16 = (n & 1) ? (unsigned)f2bf(hnv[1]) : (unsigned)f2bf(other);
      unsigned dw = lo16 | (hi16 << 16);
      if ((t >> 1) & 1) dw |= PARM;
      unsigned* dst = hb32 + (t&1)*(BATCH*HID/2)
                    + (size_t)(b0 + lbm)*(HID/2) + (jmy >> 1);
      __hip_atomic_store(dst, dw, __ATOMIC_RELAXED, __HIP_MEMORY_SCOPE_AGENT);
    }

    // ---- out/hidb HBM stores: off the critical path; acks retired by the
    //      next step's llc_load_h vmcnt(0)
    #pragma unroll
    for (int u = 0; u < 2; ++u) {
      int lb = mtile*16 + q*4 + rgb + u;
      int bb = b0 + lb;
      out [(size_t)(t*BATCH + bb)*HID + jmy]       = hnv[u];
      hidb[((size_t)(t*2+0)*BATCH + bb)*HID + jmy] = hrv[u];
      hidb[((size_t)(t*2+1)*BATCH + bb)*HID + jmy] = crv[u];
    }
  }
}

extern "C" void kernel_launch(void* const* d_in, const int* in_sizes, int n_in,
                              void* d_out, int out_size, void* d_ws, size_t ws_size,
                              hipStream_t stream) {
  (void)in_sizes; (void)n_in; (void)out_size; (void)ws_size;
  const float* x   = (const float*)d_in[0];
  const int*   dn  = (const int*)  d_in[1];
  const float* Wih = (const float*)d_in[2];
  const float* Whh = (const float*)d_in[3];
  const float* bih = (const float*)d_in[4];
  const float* bhh = (const float*)d_in[5];
  float* out = (float*)d_out;

  unsigned*           hb32 = (unsigned*)d_ws;
  unsigned long long* hb64 = (unsigned long long*)d_ws;
  size_t hbuf_bytes = (size_t)2*BATCH*HID*sizeof(unsigned short);   // 512 KB
  int* flags = (int*)((char*)d_ws + hbuf_bytes);                    // unused

  // 0x40 pattern: bf16 parity bit14 = 1 everywhere => step-0 consumers
  // validate immediately; masked value 0x0040 (~3e-39) acts as h(-1)=0.
  hipMemsetAsync(d_ws, 0x40, hbuf_bytes, stream);
  hipFuncSetAttribute((const void*)lstm_fused,
                      hipFuncAttributeMaxDynamicSharedMemorySize, LDS_BYTES);
  lstm_fused<<<dim3(NWG), dim3(NTHR), LDS_BYTES, stream>>>(
      x, dn, Wih, Whh, bih, bhh, out, hb32, hb64, flags);
}